// Round 1
// baseline (404.261 us; speedup 1.0000x reference)
//
#include <hip/hip_runtime.h>
#include <hip/hip_bf16.h>

#define BATCH 32768
#define TSEQ 200

typedef __attribute__((ext_vector_type(8))) short short8;
typedef __attribute__((ext_vector_type(4))) float floatx4;

__device__ __forceinline__ float fast_sigmoid(float x) {
    return __builtin_amdgcn_rcpf(1.0f + __expf(-x));
}
__device__ __forceinline__ float fast_tanh(float x) {
    float e = __expf(2.0f * x);
    return 1.0f - 2.0f * __builtin_amdgcn_rcpf(e + 1.0f);
}
__device__ __forceinline__ short f2bfs(float v) {
    __hip_bfloat16 h = __float2bfloat16(v);
    return __builtin_bit_cast(short, h);
}

// ---------------- workspace layout (bytes) ----------------
// hh   : bf16 [2][B][200][4]              = 104,857,600
// WHbf : bf16 [128][800]                  =     204,800
// WLbf : bf16 [128][800]                  =     204,800
// W1bf : bf16 [80][256]                   =      40,960
// W2bf : bf16 [48][96] (zero padded)      =       9,216
// u    : f32  [401]  (u[400] = s0)        =       1,616
// otherp: f32 [2][B]                      =     262,144
#define WS_HH  0
#define WS_WHB 104857600
#define WS_WLB (WS_WHB + 204800)
#define WS_W1B (WS_WLB + 204800)
#define WS_W2B (WS_W1B + 40960)
#define WS_U   (WS_W2B + 9216)
#define WS_OT  (WS_U + 1616)

struct LW { const float* p[16]; };

// ---------------- kernel 0: weight prep / folds ----------------
__global__ __launch_bounds__(256) void k_prep(
    const float* __restrict__ WH, const float* __restrict__ WL,
    const float* __restrict__ W1, const float* __restrict__ W2,
    const float* __restrict__ W3, const float* __restrict__ Wp,
    const float* __restrict__ bp, const float* __restrict__ b3,
    __hip_bfloat16* __restrict__ WHbf, __hip_bfloat16* __restrict__ WLbf,
    __hip_bfloat16* __restrict__ W1bf, __hip_bfloat16* __restrict__ W2bf,
    float* __restrict__ u)
{
    int gid = blockIdx.x * 256 + threadIdx.x;   // 400 blocks -> 102400 threads
    WHbf[gid] = __float2bfloat16(WH[gid]);
    WLbf[gid] = __float2bfloat16(WL[gid]);
    if (gid < 20480) W1bf[gid] = __float2bfloat16(W1[gid]);
    if (gid < 4608) {
        int rr = gid / 96, cc = gid - rr * 96;
        float v = (rr < 40 && cc < 80) ? W2[rr * 80 + cc] : 0.0f;
        W2bf[gid] = __float2bfloat16(v);
    }
    if (gid < 400) {
        float a = 0.f;
        for (int j = 0; j < 40; ++j) a = fmaf(W3[40 + j], Wp[j * 400 + gid], a);
        u[gid] = a;
    } else if (gid == 400) {
        float a = b3[0];
        for (int j = 0; j < 40; ++j) a = fmaf(W3[40 + j], bp[j], a);
        u[400] = a;
    }
}

// ---------------- kernel 1: fused 2-layer LSTM (both rnns) ----------------
// 4 lanes per (b, r): lane q owns h-dim q; full h gathered by __shfl in-quad.
__global__ __launch_bounds__(256) void k_lstm(
    const float* __restrict__ x, LW w, const float* __restrict__ u,
    __hip_bfloat16* __restrict__ hh, float* __restrict__ otherp)
{
    int gid = blockIdx.x * 256 + threadIdx.x;
    int q = gid & 3;
    int group = gid >> 2;           // (b, r) element id
    int b = group & (BATCH - 1);
    int r = group >> 15;            // 0: H-stream, 1: L-stream

    const float* Wih0 = w.p[r * 8 + 0];
    const float* Whh0 = w.p[r * 8 + 1];
    const float* bih0 = w.p[r * 8 + 2];
    const float* bhh0 = w.p[r * 8 + 3];
    const float* Wih1 = w.p[r * 8 + 4];
    const float* Whh1 = w.p[r * 8 + 5];
    const float* bih1 = w.p[r * 8 + 6];
    const float* bhh1 = w.p[r * 8 + 7];

    // gate G in {i,f,g,o}: row j = 4*G + q of the [16,H] weight mats
    float wx0[4], bb0[4], bb1[4], whh0[4][4], wih1[4][4], whh1[4][4];
#pragma unroll
    for (int G = 0; G < 4; ++G) {
        int j = 4 * G + q;
        wx0[G] = Wih0[j];
        bb0[G] = bih0[j] + bhh0[j];
        bb1[G] = bih1[j] + bhh1[j];
#pragma unroll
        for (int k = 0; k < 4; ++k) {
            whh0[G][k] = Whh0[j * 4 + k];
            wih1[G][k] = Wih1[j * 4 + k];
            whh1[G][k] = Whh1[j * 4 + k];
        }
    }

    int lane = threadIdx.x & 63;
    int base = lane & ~3;
    const float* xp = x + ((size_t)b * 2 + r) * TSEQ;
    const float* up = u + r * TSEQ;
    __hip_bfloat16* hp = hh + ((size_t)r * BATCH + b) * (4 * TSEQ) + q;

    float h0 = 0.f, c0 = 0.f, h1 = 0.f, c1 = 0.f, accO = 0.f;

#pragma unroll 2
    for (int t = 0; t < TSEQ; ++t) {
        float xt = xp[t];
        accO = fmaf(xt, up[t], accO);   // folded "other" contribution

        // ---- layer 0 ----
        float a0 = __shfl(h0, base + 0, 64);
        float a1 = __shfl(h0, base + 1, 64);
        float a2 = __shfl(h0, base + 2, 64);
        float a3 = __shfl(h0, base + 3, 64);
        float g[4];
#pragma unroll
        for (int G = 0; G < 4; ++G) {
            float t0 = fmaf(xt, wx0[G], bb0[G]);
            t0 = fmaf(whh0[G][0], a0, t0);
            t0 = fmaf(whh0[G][1], a1, t0);
            t0 = fmaf(whh0[G][2], a2, t0);
            t0 = fmaf(whh0[G][3], a3, t0);
            g[G] = t0;
        }
        float ig = fast_sigmoid(g[0]);
        float fg = fast_sigmoid(g[1]);
        float gg = fast_tanh(g[2]);
        float og = fast_sigmoid(g[3]);
        c0 = fmaf(fg, c0, ig * gg);
        h0 = og * fast_tanh(c0);

        // ---- layer 1 ----
        float p0 = __shfl(h0, base + 0, 64);
        float p1 = __shfl(h0, base + 1, 64);
        float p2 = __shfl(h0, base + 2, 64);
        float p3 = __shfl(h0, base + 3, 64);
        float q0 = __shfl(h1, base + 0, 64);
        float q1 = __shfl(h1, base + 1, 64);
        float q2 = __shfl(h1, base + 2, 64);
        float q3 = __shfl(h1, base + 3, 64);
#pragma unroll
        for (int G = 0; G < 4; ++G) {
            float t0 = bb1[G];
            t0 = fmaf(wih1[G][0], p0, t0);
            t0 = fmaf(wih1[G][1], p1, t0);
            t0 = fmaf(wih1[G][2], p2, t0);
            t0 = fmaf(wih1[G][3], p3, t0);
            t0 = fmaf(whh1[G][0], q0, t0);
            t0 = fmaf(whh1[G][1], q1, t0);
            t0 = fmaf(whh1[G][2], q2, t0);
            t0 = fmaf(whh1[G][3], q3, t0);
            g[G] = t0;
        }
        ig = fast_sigmoid(g[0]);
        fg = fast_sigmoid(g[1]);
        gg = fast_tanh(g[2]);
        og = fast_sigmoid(g[3]);
        c1 = fmaf(fg, c1, ig * gg);
        h1 = og * fast_tanh(c1);

        hp[t * 4] = __float2bfloat16(h1);   // Hh[b, t, q] (bf16 for the MFMA GEMM)
    }
    if (q == 0) otherp[(size_t)r * BATCH + b] = accO;
}

// ---------------- kernel 2: bf16 MFMA GEMMs + fused MLP tail ----------------
// block = 256 thr (4 waves), 64 rows per block. 16x16x32 bf16 MFMA.
// A-frag: lane holds A[m=lane&15][k=(lane>>4)*8 + j]; B-frag: W row-major same pattern.
// C/D:    col = lane&15, row = (lane>>4)*4 + reg   [measured m89/m91]
__global__ __launch_bounds__(256) void k_head(
    const __hip_bfloat16* __restrict__ hh,
    const __hip_bfloat16* __restrict__ WHbf, const __hip_bfloat16* __restrict__ WLbf,
    const __hip_bfloat16* __restrict__ W1bf, const __hip_bfloat16* __restrict__ W2bf,
    const float* __restrict__ bH, const float* __restrict__ bL,
    const float* __restrict__ b1, const float* __restrict__ b2,
    const float* __restrict__ W3, const float* __restrict__ u,
    const float* __restrict__ otherp, float* __restrict__ out)
{
    __shared__ short zsh[64 * 264];    // z   [64][256] bf16, row stride 264 (conflict pad)
    __shared__ short z1sh[64 * 104];   // z1  [64][96]  bf16 (K-pad zeros), stride 104
    __shared__ float z2sh[64 * 49];    // z2  [64][40]  f32, stride 49
    int tid = threadIdx.x;
    int wv = tid >> 6;
    int lane = tid & 63;
    int l15 = lane & 15;
    int quad = lane >> 4;
    int m0 = blockIdx.x * 64;

    // zero z1 K-pad columns (80..103)
    for (int i = tid; i < 64 * 24; i += 256) {
        int rr = i / 24, cc = 80 + (i - rr * 24);
        z1sh[rr * 104 + cc] = 0;
    }

    // phase A: Hf = tanh(Hh@WH.T + bH), Lf = tanh(Lh@WL.T + bL)  -> zsh[., 0:256]
    for (int f = 0; f < 2; ++f) {
        const __hip_bfloat16* A = hh + (size_t)f * BATCH * (4 * TSEQ);
        const __hip_bfloat16* Wb = f ? WLbf : WHbf;
        const float* bias = f ? bL : bH;
        floatx4 acc[8] = {};
        const short8* arow = (const short8*)(const void*)
            (A + (size_t)(m0 + wv * 16 + l15) * 800 + quad * 8);
        for (int kc = 0; kc < 25; ++kc) {
            short8 af = arow[kc * 4];
#pragma unroll
            for (int nt = 0; nt < 8; ++nt) {
                const short8* brow = (const short8*)(const void*)
                    (Wb + (size_t)(nt * 16 + l15) * 800 + quad * 8);
                short8 bfr = brow[kc * 4];
                acc[nt] = __builtin_amdgcn_mfma_f32_16x16x32_bf16(af, bfr, acc[nt], 0, 0, 0);
            }
        }
#pragma unroll
        for (int nt = 0; nt < 8; ++nt) {
            int n = nt * 16 + l15;
            float bb = bias[n];
#pragma unroll
            for (int rg = 0; rg < 4; ++rg) {
                int ml = wv * 16 + quad * 4 + rg;
                zsh[ml * 264 + f * 128 + n] = f2bfs(fast_tanh(acc[nt][rg] + bb));
            }
        }
    }
    __syncthreads();

    // phase B: z1 = tanh(z @ W1.T + b1)   M=64 K=256 N=80
    {
        floatx4 acc[5] = {};
#pragma unroll
        for (int kc = 0; kc < 8; ++kc) {
            short8 af = *(const short8*)(const void*)
                &zsh[(wv * 16 + l15) * 264 + kc * 32 + quad * 8];
#pragma unroll
            for (int nt = 0; nt < 5; ++nt) {
                short8 bfr = *(const short8*)(const void*)
                    (W1bf + (size_t)(nt * 16 + l15) * 256 + kc * 32 + quad * 8);
                acc[nt] = __builtin_amdgcn_mfma_f32_16x16x32_bf16(af, bfr, acc[nt], 0, 0, 0);
            }
        }
#pragma unroll
        for (int nt = 0; nt < 5; ++nt) {
            int n = nt * 16 + l15;
            float bb = b1[n];
#pragma unroll
            for (int rg = 0; rg < 4; ++rg) {
                int ml = wv * 16 + quad * 4 + rg;
                z1sh[ml * 104 + n] = f2bfs(fast_tanh(acc[nt][rg] + bb));
            }
        }
    }
    __syncthreads();

    // phase C: z2 = tanh(z1 @ W2.T + b2)  M=64 K=96(pad) N=48(pad, keep 40)
    {
        floatx4 acc[3] = {};
#pragma unroll
        for (int kc = 0; kc < 3; ++kc) {
            short8 af = *(const short8*)(const void*)
                &z1sh[(wv * 16 + l15) * 104 + kc * 32 + quad * 8];
#pragma unroll
            for (int nt = 0; nt < 3; ++nt) {
                short8 bfr = *(const short8*)(const void*)
                    (W2bf + (size_t)(nt * 16 + l15) * 96 + kc * 32 + quad * 8);
                acc[nt] = __builtin_amdgcn_mfma_f32_16x16x32_bf16(af, bfr, acc[nt], 0, 0, 0);
            }
        }
#pragma unroll
        for (int nt = 0; nt < 3; ++nt) {
            int n = nt * 16 + l15;
            if (n < 40) {
                float bb = b2[n];
#pragma unroll
                for (int rg = 0; rg < 4; ++rg) {
                    int ml = wv * 16 + quad * 4 + rg;
                    z2sh[ml * 49 + n] = fast_tanh(acc[nt][rg] + bb);
                }
            }
        }
    }
    __syncthreads();

    // phase D: logit = z2.w3a + (folded other) -> sigmoid
    if (tid < 64) {
        int grow = m0 + tid;
        float s = u[400] + otherp[grow] + otherp[BATCH + grow];
        for (int j = 0; j < 40; ++j) s = fmaf(z2sh[tid * 49 + j], W3[j], s);
        out[grow] = fast_sigmoid(s);
    }
}

extern "C" void kernel_launch(void* const* d_in, const int* in_sizes, int n_in,
                              void* d_out, int out_size, void* d_ws, size_t ws_size,
                              hipStream_t stream)
{
    const float* x = (const float*)d_in[0];
    LW w;
    for (int i = 0; i < 16; ++i) w.p[i] = (const float*)d_in[1 + i];
    const float* Wp = (const float*)d_in[17];
    const float* bp = (const float*)d_in[18];
    const float* WH = (const float*)d_in[19];
    const float* bH = (const float*)d_in[20];
    const float* WL = (const float*)d_in[21];
    const float* bL = (const float*)d_in[22];
    const float* W1 = (const float*)d_in[23];
    const float* b1 = (const float*)d_in[24];
    const float* W2 = (const float*)d_in[25];
    const float* b2 = (const float*)d_in[26];
    const float* W3 = (const float*)d_in[27];
    const float* b3 = (const float*)d_in[28];

    char* ws = (char*)d_ws;
    __hip_bfloat16* hh   = (__hip_bfloat16*)(ws + WS_HH);
    __hip_bfloat16* WHbf = (__hip_bfloat16*)(ws + WS_WHB);
    __hip_bfloat16* WLbf = (__hip_bfloat16*)(ws + WS_WLB);
    __hip_bfloat16* W1bf = (__hip_bfloat16*)(ws + WS_W1B);
    __hip_bfloat16* W2bf = (__hip_bfloat16*)(ws + WS_W2B);
    float* u      = (float*)(ws + WS_U);
    float* otherp = (float*)(ws + WS_OT);
    float* out = (float*)d_out;

    k_prep<<<400, 256, 0, stream>>>(WH, WL, W1, W2, W3, Wp, bp, b3,
                                    WHbf, WLbf, W1bf, W2bf, u);
    k_lstm<<<1024, 256, 0, stream>>>(x, w, u, hh, otherp);
    k_head<<<512, 256, 0, stream>>>(hh, WHbf, WLbf, W1bf, W2bf,
                                    bH, bL, b1, b2, W3, u, otherp, out);
}

// Round 2
// 364.447 us; speedup vs baseline: 1.1092x; 1.1092x over previous
//
#include <hip/hip_runtime.h>
#include <hip/hip_bf16.h>

#define BATCH 32768
#define TSEQ 200

typedef __attribute__((ext_vector_type(8))) short short8;
typedef __attribute__((ext_vector_type(4))) float floatx4;
typedef __attribute__((ext_vector_type(2))) float f32x2;

__device__ __forceinline__ float fast_sigmoid(float x) {
    return __builtin_amdgcn_rcpf(1.0f + __expf(-x));
}
__device__ __forceinline__ float fast_tanh(float x) {
    float e = __expf(2.0f * x);
    return 1.0f - 2.0f * __builtin_amdgcn_rcpf(e + 1.0f);
}
__device__ __forceinline__ short f2bfs(float v) {
    __hip_bfloat16 h = __float2bfloat16(v);
    return __builtin_bit_cast(short, h);
}
__device__ __forceinline__ f32x2 splat2(float x) { f32x2 v; v[0] = x; v[1] = x; return v; }
__device__ __forceinline__ f32x2 pkfma(f32x2 a, f32x2 b, f32x2 c) {
    return __builtin_elementwise_fma(a, b, c);
}
// broadcast lane (quad_base + K) to all 4 lanes of the quad — pure VALU, no LDS pipe
template <int K>
__device__ __forceinline__ float qb(float v) {
    int i = __builtin_bit_cast(int, v);
    int r = __builtin_amdgcn_update_dpp(i, i, K * 0x55, 0xf, 0xf, false);
    return __builtin_bit_cast(float, r);
}
// async global->LDS, 16B per lane; lds ptr must be wave-uniform base (+lane*16 implicit)
__device__ __forceinline__ void async16(void* lds, const void* g) {
    __builtin_amdgcn_global_load_lds(
        (const __attribute__((address_space(1))) unsigned int*)g,
        (__attribute__((address_space(3))) unsigned int*)lds, 16, 0, 0);
}

// ---------------- workspace layout (bytes) ----------------
#define WS_HH  0                         // bf16 [2][B][200*4]      104,857,600
#define WS_WHB 104857600                 // bf16 [128][800]
#define WS_WLB (WS_WHB + 204800)
#define WS_W1B (WS_WLB + 204800)         // bf16 [80][256]
#define WS_W2B (WS_W1B + 40960)          // bf16 [48][96] zero-pad
#define WS_U   (WS_W2B + 9216)           // f32 [401]
#define WS_OT  (WS_U + 1616)             // f32 [2][B]
#define WS_Z   (WS_OT + 262144)          // bf16 [B][256] = 16,777,216

struct LW { const float* p[16]; };

// ---------------- kernel 0: weight prep / folds ----------------
__global__ __launch_bounds__(256) void k_prep(
    const float* __restrict__ WH, const float* __restrict__ WL,
    const float* __restrict__ W1, const float* __restrict__ W2,
    const float* __restrict__ W3, const float* __restrict__ Wp,
    const float* __restrict__ bp, const float* __restrict__ b3,
    __hip_bfloat16* __restrict__ WHbf, __hip_bfloat16* __restrict__ WLbf,
    __hip_bfloat16* __restrict__ W1bf, __hip_bfloat16* __restrict__ W2bf,
    float* __restrict__ u)
{
    int gid = blockIdx.x * 256 + threadIdx.x;   // 400 blocks
    WHbf[gid] = __float2bfloat16(WH[gid]);
    WLbf[gid] = __float2bfloat16(WL[gid]);
    if (gid < 20480) W1bf[gid] = __float2bfloat16(W1[gid]);
    if (gid < 4608) {
        int rr = gid / 96, cc = gid - rr * 96;
        float v = (rr < 40 && cc < 80) ? W2[rr * 80 + cc] : 0.0f;
        W2bf[gid] = __float2bfloat16(v);
    }
    if (gid < 400) {
        float a = 0.f;
        for (int j = 0; j < 40; ++j) a = fmaf(W3[40 + j], Wp[j * 400 + gid], a);
        u[gid] = a;
    } else if (gid == 400) {
        float a = b3[0];
        for (int j = 0; j < 40; ++j) a = fmaf(W3[40 + j], bp[j], a);
        u[400] = a;
    }
}

// ---------------- kernel 1: fused 2-layer LSTM (both rnns) ----------------
// 4 lanes per (b,r); h broadcast via DPP quad_perm; gate dots in v_pk_fma_f32.
__global__ __launch_bounds__(256) void k_lstm(
    const float* __restrict__ x, LW w, const float* __restrict__ u,
    __hip_bfloat16* __restrict__ hh, float* __restrict__ otherp)
{
    int gid = blockIdx.x * 256 + threadIdx.x;
    int q = gid & 3;
    int group = gid >> 2;
    int b = group & (BATCH - 1);
    int r = group >> 15;                 // wave-uniform (512 blocks per r)

    const float* Wih0 = w.p[r * 8 + 0];
    const float* Whh0 = w.p[r * 8 + 1];
    const float* bih0 = w.p[r * 8 + 2];
    const float* bhh0 = w.p[r * 8 + 3];
    const float* Wih1 = w.p[r * 8 + 4];
    const float* Whh1 = w.p[r * 8 + 5];
    const float* bih1 = w.p[r * 8 + 6];
    const float* bhh1 = w.p[r * 8 + 7];

    // gate pairs: p=0 -> (i,f), p=1 -> (g,o); row j = 4*G + q
    f32x2 wx0p[2], bb0p[2], bb1p[2], whh0p[2][4], wih1p[2][4], whh1p[2][4];
#pragma unroll
    for (int p = 0; p < 2; ++p) {
#pragma unroll
        for (int c = 0; c < 2; ++c) {
            int G = 2 * p + c;
            int j = 4 * G + q;
            wx0p[p][c] = Wih0[j];
            bb0p[p][c] = bih0[j] + bhh0[j];
            bb1p[p][c] = bih1[j] + bhh1[j];
#pragma unroll
            for (int k = 0; k < 4; ++k) {
                whh0p[p][k][c] = Whh0[j * 4 + k];
                wih1p[p][k][c] = Wih1[j * 4 + k];
                whh1p[p][k][c] = Whh1[j * 4 + k];
            }
        }
    }

    const float* xp = x + ((size_t)b * 2 + r) * TSEQ;
    const float* up = u + r * TSEQ;
    __hip_bfloat16* hp = hh + ((size_t)r * BATCH + b) * (4 * TSEQ) + q;

    float h0 = 0.f, c0 = 0.f, h1 = 0.f, c1 = 0.f, accO = 0.f;

    for (int tb = 0; tb < TSEQ; tb += 4) {
        float4 xv = *(const float4*)(xp + tb);
        float4 uv = *(const float4*)(up + tb);
        float xa[4] = {xv.x, xv.y, xv.z, xv.w};
        float ua[4] = {uv.x, uv.y, uv.z, uv.w};
#pragma unroll
        for (int j = 0; j < 4; ++j) {
            float xt = xa[j];
            accO = fmaf(xt, ua[j], accO);

            // ---- layer 0 ----
            float a0 = qb<0>(h0), a1 = qb<1>(h0), a2 = qb<2>(h0), a3 = qb<3>(h0);
            f32x2 g0 = pkfma(splat2(xt), wx0p[0], bb0p[0]);
            f32x2 g1 = pkfma(splat2(xt), wx0p[1], bb0p[1]);
            g0 = pkfma(whh0p[0][0], splat2(a0), g0); g1 = pkfma(whh0p[1][0], splat2(a0), g1);
            g0 = pkfma(whh0p[0][1], splat2(a1), g0); g1 = pkfma(whh0p[1][1], splat2(a1), g1);
            g0 = pkfma(whh0p[0][2], splat2(a2), g0); g1 = pkfma(whh0p[1][2], splat2(a2), g1);
            g0 = pkfma(whh0p[0][3], splat2(a3), g0); g1 = pkfma(whh0p[1][3], splat2(a3), g1);
            float ig = fast_sigmoid(g0[0]);
            float fg = fast_sigmoid(g0[1]);
            float gg = fast_tanh(g1[0]);
            float og = fast_sigmoid(g1[1]);
            c0 = fmaf(fg, c0, ig * gg);
            h0 = og * fast_tanh(c0);

            // ---- layer 1 ----
            float p0 = qb<0>(h0), p1 = qb<1>(h0), p2 = qb<2>(h0), p3 = qb<3>(h0);
            float q0 = qb<0>(h1), q1 = qb<1>(h1), q2 = qb<2>(h1), q3 = qb<3>(h1);
            g0 = bb1p[0]; g1 = bb1p[1];
            g0 = pkfma(wih1p[0][0], splat2(p0), g0); g1 = pkfma(wih1p[1][0], splat2(p0), g1);
            g0 = pkfma(wih1p[0][1], splat2(p1), g0); g1 = pkfma(wih1p[1][1], splat2(p1), g1);
            g0 = pkfma(wih1p[0][2], splat2(p2), g0); g1 = pkfma(wih1p[1][2], splat2(p2), g1);
            g0 = pkfma(wih1p[0][3], splat2(p3), g0); g1 = pkfma(wih1p[1][3], splat2(p3), g1);
            g0 = pkfma(whh1p[0][0], splat2(q0), g0); g1 = pkfma(whh1p[1][0], splat2(q0), g1);
            g0 = pkfma(whh1p[0][1], splat2(q1), g0); g1 = pkfma(whh1p[1][1], splat2(q1), g1);
            g0 = pkfma(whh1p[0][2], splat2(q2), g0); g1 = pkfma(whh1p[1][2], splat2(q2), g1);
            g0 = pkfma(whh1p[0][3], splat2(q3), g0); g1 = pkfma(whh1p[1][3], splat2(q3), g1);
            ig = fast_sigmoid(g0[0]);
            fg = fast_sigmoid(g0[1]);
            gg = fast_tanh(g1[0]);
            og = fast_sigmoid(g1[1]);
            c1 = fmaf(fg, c1, ig * gg);
            h1 = og * fast_tanh(c1);

            hp[(tb + j) * 4] = __float2bfloat16(h1);
        }
    }
    if (q == 0) otherp[(size_t)r * BATCH + b] = accO;
}

// ---------------- kernel 2: pipelined bf16 GEMM  z = tanh(hh @ W.T + b) ----------------
// grid (256, 2): 128 rows x 128 cols per block, K=800 in chunks of 32, LDS double-buffered.
__global__ __launch_bounds__(256) void k_gemm(
    const __hip_bfloat16* __restrict__ hh,
    const __hip_bfloat16* __restrict__ WHbf, const __hip_bfloat16* __restrict__ WLbf,
    const float* __restrict__ bH, const float* __restrict__ bL,
    __hip_bfloat16* __restrict__ zws)
{
    __shared__ __hip_bfloat16 As[2][128 * 32];   // 8KB each
    __shared__ __hip_bfloat16 Bs[2][128 * 32];
    int tid = threadIdx.x;
    int f = blockIdx.y;
    int m0 = blockIdx.x * 128;
    const __hip_bfloat16* A = hh + (size_t)f * BATCH * 800 + (size_t)m0 * 800;
    const __hip_bfloat16* Wb = f ? WLbf : WHbf;
    const float* bias = f ? bL : bH;

    int wv = tid >> 6, lane = tid & 63, l15 = lane & 15, quad = lane >> 4;
    // staging: thread tid covers (row=tid>>2, seg=tid&3) then row+64
    const __hip_bfloat16* ga = A + (size_t)(tid >> 2) * 800 + (tid & 3) * 8;
    const __hip_bfloat16* gb = Wb + (size_t)(tid >> 2) * 800 + (tid & 3) * 8;

    floatx4 acc[2][8] = {};

#define PREFETCH(kc, buf)                                              \
    do {                                                               \
        __hip_bfloat16* la = &As[buf][wv * 512];                       \
        __hip_bfloat16* lb = &Bs[buf][wv * 512];                       \
        async16(la,        ga + (kc) * 32);                            \
        async16(lb,        gb + (kc) * 32);                            \
        async16(la + 2048, ga + 64 * 800 + (kc) * 32);                 \
        async16(lb + 2048, gb + 64 * 800 + (kc) * 32);                 \
    } while (0)

    PREFETCH(0, 0);
    for (int kc = 0; kc < 25; ++kc) {
        __syncthreads();                      // drains vmcnt -> buf[kc&1] ready
        if (kc < 24) PREFETCH(kc + 1, (kc + 1) & 1);
        int buf = kc & 1;
        short8 af0 = *(const short8*)(const void*)&As[buf][(wv * 32 + l15) * 32 + quad * 8];
        short8 af1 = *(const short8*)(const void*)&As[buf][(wv * 32 + 16 + l15) * 32 + quad * 8];
#pragma unroll
        for (int nt = 0; nt < 8; ++nt) {
            short8 bfr = *(const short8*)(const void*)&Bs[buf][(nt * 16 + l15) * 32 + quad * 8];
            acc[0][nt] = __builtin_amdgcn_mfma_f32_16x16x32_bf16(af0, bfr, acc[0][nt], 0, 0, 0);
            acc[1][nt] = __builtin_amdgcn_mfma_f32_16x16x32_bf16(af1, bfr, acc[1][nt], 0, 0, 0);
        }
    }
#undef PREFETCH

    float bv[8];
#pragma unroll
    for (int nt = 0; nt < 8; ++nt) bv[nt] = bias[nt * 16 + l15];
#pragma unroll
    for (int mt = 0; mt < 2; ++mt)
#pragma unroll
        for (int nt = 0; nt < 8; ++nt)
#pragma unroll
            for (int rg = 0; rg < 4; ++rg) {
                int row = m0 + wv * 32 + mt * 16 + quad * 4 + rg;
                int col = f * 128 + nt * 16 + l15;
                zws[(size_t)row * 256 + col] =
                    __float2bfloat16(fast_tanh(acc[mt][nt][rg] + bv[nt]));
            }
}

// ---------------- kernel 3: MLP tail on z ----------------
__global__ __launch_bounds__(256) void k_tail(
    const __hip_bfloat16* __restrict__ zws,
    const __hip_bfloat16* __restrict__ W1bf, const __hip_bfloat16* __restrict__ W2bf,
    const float* __restrict__ b1, const float* __restrict__ b2,
    const float* __restrict__ W3, const float* __restrict__ u,
    const float* __restrict__ otherp, float* __restrict__ out)
{
    __shared__ short z1sh[64 * 104];   // z1 [64][96] bf16 (K-pad zeros), stride 104
    __shared__ float z2sh[64 * 49];    // z2 [64][40] f32, stride 49
    int tid = threadIdx.x;
    int wv = tid >> 6, lane = tid & 63, l15 = lane & 15, quad = lane >> 4;
    int m0 = blockIdx.x * 64;

    for (int i = tid; i < 64 * 24; i += 256) {          // zero z1 K-pad cols 80..103
        int rr = i / 24, cc = 80 + (i - rr * 24);
        z1sh[rr * 104 + cc] = 0;
    }

    // phase B: z1 = tanh(z @ W1.T + b1)   M=64 K=256 N=80
    {
        floatx4 acc[5] = {};
#pragma unroll
        for (int kc = 0; kc < 8; ++kc) {
            short8 af = *(const short8*)(const void*)
                (zws + (size_t)(m0 + wv * 16 + l15) * 256 + kc * 32 + quad * 8);
#pragma unroll
            for (int nt = 0; nt < 5; ++nt) {
                short8 bfr = *(const short8*)(const void*)
                    (W1bf + (size_t)(nt * 16 + l15) * 256 + kc * 32 + quad * 8);
                acc[nt] = __builtin_amdgcn_mfma_f32_16x16x32_bf16(af, bfr, acc[nt], 0, 0, 0);
            }
        }
#pragma unroll
        for (int nt = 0; nt < 5; ++nt) {
            int n = nt * 16 + l15;
            float bb = b1[n];
#pragma unroll
            for (int rg = 0; rg < 4; ++rg) {
                int ml = wv * 16 + quad * 4 + rg;
                z1sh[ml * 104 + n] = f2bfs(fast_tanh(acc[nt][rg] + bb));
            }
        }
    }
    __syncthreads();

    // phase C: z2 = tanh(z1 @ W2.T + b2)  M=64 K=96(pad) N=48(keep 40)
    {
        floatx4 acc[3] = {};
#pragma unroll
        for (int kc = 0; kc < 3; ++kc) {
            short8 af = *(const short8*)(const void*)
                &z1sh[(wv * 16 + l15) * 104 + kc * 32 + quad * 8];
#pragma unroll
            for (int nt = 0; nt < 3; ++nt) {
                short8 bfr = *(const short8*)(const void*)
                    (W2bf + (size_t)(nt * 16 + l15) * 96 + kc * 32 + quad * 8);
                acc[nt] = __builtin_amdgcn_mfma_f32_16x16x32_bf16(af, bfr, acc[nt], 0, 0, 0);
            }
        }
#pragma unroll
        for (int nt = 0; nt < 3; ++nt) {
            int n = nt * 16 + l15;
            if (n < 40) {
                float bb = b2[n];
#pragma unroll
                for (int rg = 0; rg < 4; ++rg) {
                    int ml = wv * 16 + quad * 4 + rg;
                    z2sh[ml * 49 + n] = fast_tanh(acc[nt][rg] + bb);
                }
            }
        }
    }
    __syncthreads();

    // phase D: logit = z2.W3[0:40] + folded(other) -> sigmoid
    if (tid < 64) {
        int grow = m0 + tid;
        float s = u[400] + otherp[grow] + otherp[BATCH + grow];
        for (int j = 0; j < 40; ++j) s = fmaf(z2sh[tid * 49 + j], W3[j], s);
        out[grow] = fast_sigmoid(s);
    }
}

extern "C" void kernel_launch(void* const* d_in, const int* in_sizes, int n_in,
                              void* d_out, int out_size, void* d_ws, size_t ws_size,
                              hipStream_t stream)
{
    const float* x = (const float*)d_in[0];
    LW w;
    for (int i = 0; i < 16; ++i) w.p[i] = (const float*)d_in[1 + i];
    const float* Wp = (const float*)d_in[17];
    const float* bp = (const float*)d_in[18];
    const float* WH = (const float*)d_in[19];
    const float* bH = (const float*)d_in[20];
    const float* WL = (const float*)d_in[21];
    const float* bL = (const float*)d_in[22];
    const float* W1 = (const float*)d_in[23];
    const float* b1 = (const float*)d_in[24];
    const float* W2 = (const float*)d_in[25];
    const float* b2 = (const float*)d_in[26];
    const float* W3 = (const float*)d_in[27];
    const float* b3 = (const float*)d_in[28];

    char* ws = (char*)d_ws;
    __hip_bfloat16* hh   = (__hip_bfloat16*)(ws + WS_HH);
    __hip_bfloat16* WHbf = (__hip_bfloat16*)(ws + WS_WHB);
    __hip_bfloat16* WLbf = (__hip_bfloat16*)(ws + WS_WLB);
    __hip_bfloat16* W1bf = (__hip_bfloat16*)(ws + WS_W1B);
    __hip_bfloat16* W2bf = (__hip_bfloat16*)(ws + WS_W2B);
    float* u      = (float*)(ws + WS_U);
    float* otherp = (float*)(ws + WS_OT);
    __hip_bfloat16* zws = (__hip_bfloat16*)(ws + WS_Z);
    float* out = (float*)d_out;

    k_prep<<<400, 256, 0, stream>>>(WH, WL, W1, W2, W3, Wp, bp, b3,
                                    WHbf, WLbf, W1bf, W2bf, u);
    k_lstm<<<1024, 256, 0, stream>>>(x, w, u, hh, otherp);
    k_gemm<<<dim3(256, 2), 256, 0, stream>>>(hh, WHbf, WLbf, bH, bL, zws);
    k_tail<<<512, 256, 0, stream>>>(zws, W1bf, W2bf, b1, b2, W3, u, otherp, out);
}